// Round 16
// baseline (547.098 us; speedup 1.0000x reference)
//
#include <hip/hip_runtime.h>
#include <hip/hip_fp16.h>
#include <math.h>

#define FEAT 2048
#define HD 1024
#define FH 4096
#define NN 8192

using s16x8 = __attribute__((ext_vector_type(8))) short;
using f32x4 = __attribute__((ext_vector_type(4))) float;
using u32x4 = __attribute__((ext_vector_type(4))) unsigned int;

#define GLOBAL_AS __attribute__((address_space(1)))
#define LDS_AS __attribute__((address_space(3)))

__device__ __forceinline__ void gload_lds16(const void* g, void* l) {
    __builtin_amdgcn_global_load_lds((const GLOBAL_AS unsigned int*)g,
                                     (LDS_AS unsigned int*)l, 16, 0, 0);
}

__device__ __forceinline__ unsigned short f2bf(float f) {
    union { float f; unsigned u; } v; v.f = f;
    unsigned r = v.u + 0x7FFFu + ((v.u >> 16) & 1u);  // RNE
    return (unsigned short)(r >> 16);
}

__device__ __forceinline__ float fast_sig(float x) { return 1.0f / (1.0f + __expf(-x)); }
__device__ __forceinline__ float fast_tanh(float x) {
    float ax = fabsf(x);
    float e = __expf(2.0f * ax);
    float r = 1.0f - 2.0f / (e + 1.0f);
    return copysignf(r, x);
}

// MALL-serviced (cache-bypassing) helpers: agent-scope relaxed atomics
__device__ __forceinline__ unsigned mall_load_u32(const unsigned* p) {
    return __hip_atomic_load(p, __ATOMIC_RELAXED, __HIP_MEMORY_SCOPE_AGENT);
}
__device__ __forceinline__ void mall_store_u32(unsigned* p, unsigned v) {
    __hip_atomic_store(p, v, __ATOMIC_RELAXED, __HIP_MEMORY_SCOPE_AGENT);
}
__device__ __forceinline__ void mall_store_u16(unsigned short* p, unsigned short v) {
    __hip_atomic_store(p, v, __ATOMIC_RELAXED, __HIP_MEMORY_SCOPE_AGENT);
}

// ---------------------------------------------------------------------------
// fused fp32 -> bf16 convert for feat, Wx, Wh  (+ root h/c init + flag reset)
// ---------------------------------------------------------------------------
__global__ __launch_bounds__(256) void convert_all_kernel(
    const float* __restrict__ feat, const float* __restrict__ Wx,
    const float* __restrict__ Wh, unsigned short* __restrict__ feat_b,
    unsigned short* __restrict__ Wx_b, unsigned short* __restrict__ Wh_b,
    const float* __restrict__ root_h, const float* __restrict__ root_c,
    unsigned short* __restrict__ h_buf, float* __restrict__ c_buf,
    int* __restrict__ done)
{
    const size_t g = (size_t)blockIdx.x * 256 + threadIdx.x;
    if (g < HD) { h_buf[g] = f2bf(root_h[g]); c_buf[g] = root_c[g]; }
    if (g < 16) done[g] = 0;

    const size_t n1 = (size_t)NN * FEAT;
    const size_t n2 = n1 + (size_t)FH * FEAT;
    size_t i = g * 8;
    const float* s; unsigned short* d;
    if (i < n1)      { s = feat + i;        d = feat_b + i; }
    else if (i < n2) { s = Wx + (i - n1);   d = Wx_b + (i - n1); }
    else             { s = Wh + (i - n2);   d = Wh_b + (i - n2); }
    float4 a = *(const float4*)s;
    float4 b = *(const float4*)(s + 4);
    unsigned short r[8] = {f2bf(a.x), f2bf(a.y), f2bf(a.z), f2bf(a.w),
                           f2bf(b.x), f2bf(b.y), f2bf(b.z), f2bf(b.w)};
    *(s16x8*)d = *(const s16x8*)r;
}

// ---------------------------------------------------------------------------
// xproj = feat @ Wx^T + (bx+bh). 256x256 BK=64 kk-split (R7 schedule),
// fp16 output via LDS repack (R13-proven full-sector stores).
// ---------------------------------------------------------------------------
__global__ __launch_bounds__(512, 2) void xproj_8ph(
    const unsigned short* __restrict__ Ab,
    const unsigned short* __restrict__ Bb,
    const float* __restrict__ bx, const float* __restrict__ bh,
    __half* __restrict__ xproj)
{
    __shared__ char lds[131072];
    const int tid = threadIdx.x;
    const int wid = tid >> 6;
    const int lane = tid & 63;
    const int wr = wid >> 2;
    const int wc = wid & 3;
    const int bm = blockIdx.x * 256;
    const int bn = blockIdx.y * 256;
    const int fr = lane & 15;
    const int fq = lane >> 4;

    const int srow = tid >> 3;
    const int sslot = (tid & 7) ^ (srow & 7);
    const unsigned short* gA[4];
    const unsigned short* gB[4];
    #pragma unroll
    for (int q = 0; q < 4; ++q) {
        gA[q] = Ab + (size_t)(bm + q * 64 + srow) * FEAT + sslot * 8;
        gB[q] = Bb + (size_t)(bn + q * 64 + srow) * FEAT + sslot * 8;
    }
    const int ldsoff = tid * 16;

    f32x4 acc[8][4];
    #pragma unroll
    for (int i = 0; i < 8; ++i)
        #pragma unroll
        for (int j = 0; j < 4; ++j) { f32x4 z = {0.f, 0.f, 0.f, 0.f}; acc[i][j] = z; }

    #pragma unroll
    for (int q = 0; q < 4; ++q) {
        gload_lds16(gA[q], lds + q * 8192 + ldsoff);
        gload_lds16(gB[q], lds + 32768 + q * 8192 + ldsoff);
    }

    for (int t = 0; t < 32; ++t) {
        const int d = t & 1;
        const char* LA = lds + d * 65536;
        const char* LB = LA + 32768;
        char* SA = lds + (d ^ 1) * 65536;
        char* SB = SA + 32768;
        const int knext = (t + 1) * 64;

        asm volatile("s_waitcnt vmcnt(0)" ::: "memory");
        __builtin_amdgcn_s_barrier();

        #pragma unroll
        for (int kk = 0; kk < 2; ++kk) {
            const int kbyte = kk * 64 + fq * 16;
            s16x8 aF[8], bF[4];
            #pragma unroll
            for (int i = 0; i < 8; ++i) {
                const int row = wr * 128 + i * 16 + fr;
                aF[i] = *(const s16x8*)(LA + row * 128 + (kbyte ^ ((row & 7) << 4)));
            }
            #pragma unroll
            for (int j = 0; j < 4; ++j) {
                const int row = wc * 64 + j * 16 + fr;
                bF[j] = *(const s16x8*)(LB + row * 128 + (kbyte ^ ((row & 7) << 4)));
            }
            if (t < 31) {
                if (kk == 0) {
                    #pragma unroll
                    for (int q = 0; q < 4; ++q)
                        gload_lds16(gA[q] + knext, SA + q * 8192 + ldsoff);
                } else {
                    #pragma unroll
                    for (int q = 0; q < 4; ++q)
                        gload_lds16(gB[q] + knext, SB + q * 8192 + ldsoff);
                }
            }
            __builtin_amdgcn_s_setprio(1);
            #pragma unroll
            for (int i = 0; i < 8; ++i)
                #pragma unroll
                for (int j = 0; j < 4; ++j)
                    acc[i][j] = __builtin_amdgcn_mfma_f32_16x16x32_bf16(
                        aF[i], bF[j], acc[i][j], 0, 0, 0);
            __builtin_amdgcn_s_setprio(0);
        }
    }

    // ---- epilogue: LDS repack to coalesced fp16 stores (R13) ----
    __builtin_amdgcn_s_barrier();
    char* W = lds + wid * 16384;
    #pragma unroll
    for (int j = 0; j < 4; ++j) {
        const int c_loc = j * 16 + fr;
        const int col = bn + wc * 64 + c_loc;
        const float bias = bx[col] + bh[col];
        #pragma unroll
        for (int i = 0; i < 8; ++i) {
            #pragma unroll
            for (int reg = 0; reg < 4; ++reg) {
                const int r_loc = i * 16 + fq * 4 + reg;
                const int byteo = r_loc * 128 +
                    ((((c_loc >> 3) ^ (r_loc & 7)) << 4)) + (c_loc & 7) * 2;
                *(__half*)(W + byteo) = __float2half_rn(acc[i][j][reg] + bias);
            }
        }
    }
    asm volatile("s_waitcnt lgkmcnt(0)" ::: "memory");
    #pragma unroll
    for (int k = 0; k < 16; ++k) {
        const int f = k * 64 + lane;
        const int r_loc = f >> 3;
        const int cchunk = f & 7;
        const s16x8 v = *(const s16x8*)(W + r_loc * 128 +
                                        ((cchunk ^ (r_loc & 7)) << 4));
        const int grow = bm + wr * 128 + r_loc;
        const int gcol = bn + wc * 64 + cchunk * 8;
        *(s16x8*)((unsigned short*)xproj + (size_t)grow * FH + gcol) = v;
    }
}

// ---------------------------------------------------------------------------
// Levels 0..9 fused, FENCE-FREE: h/c exchanged via agent-scope RELAXED
// atomics (MALL-serviced, bypass the non-coherent XCD L2s) -> no wbL2/invL2
// per level (R15's residual 20 us/level). Producer: atomic h/c stores ->
// vmcnt(0) -> relaxed flag add. Consumer: relaxed poll -> atomic loads
// (cache-bypassing, cannot be stale). Wh/xproj stay L2-hot across levels.
// 224 blocks x 96 KB LDS -> all co-resident (no deadlock).
// ---------------------------------------------------------------------------
__global__ __launch_bounds__(512, 2) void levels_fused_small(
    const __half* __restrict__ xproj, const unsigned short* __restrict__ Whb,
    unsigned short* __restrict__ h_buf, float* __restrict__ c_buf,
    float* __restrict__ out, int* __restrict__ done)
{
    constexpr int MR = 4;
    constexpr int ABYTES = 128 * 128;     // 16 KB per A buffer
    constexpr int BBYTES = 32768;         // 32 KB per B buffer
    __shared__ char ldsA[2 * ABYTES];     // 32 KB
    __shared__ char ldsB[2 * BBYTES];     // 64 KB
    const int bid = blockIdx.x;
    int lvl, nb;
    if (bid < 128)      { lvl = bid >> 4; nb = 0; }
    else if (bid < 160) { lvl = 8;        nb = (bid - 128) >> 4; }
    else                { lvl = 9;        nb = (bid - 160) >> 4; }
    const int jg0 = (bid & 15) * 64;
    const int start = (1 << lvl) - 1;
    const int cnt = 1 << lvl;
    const int lim = start + cnt;
    const int t0 = start + nb * 128;

    // wait for previous level: relaxed poll only (no fence)
    if (lvl > 0) {
        if (threadIdx.x == 0) {
            const int need = (lvl <= 8) ? 16 : 32;   // nblk[lvl-1]
            while (__hip_atomic_load(done + (lvl - 1), __ATOMIC_RELAXED,
                                     __HIP_MEMORY_SCOPE_AGENT) < need)
                __builtin_amdgcn_s_sleep(4);
        }
        __syncthreads();
        asm volatile("" ::: "memory");   // compiler barrier: no load hoisting
    }

    const int tid = threadIdx.x;
    const int wid = tid >> 6, lane = tid & 63;
    const int wr = wid >> 2, wc = wid & 3;
    const int fr = lane & 15, fq = lane >> 4;

    const int srow = tid >> 3;
    const int sslot = (tid & 7) ^ (srow & 7);
    const unsigned* gA[2];
    #pragma unroll
    for (int q = 0; q < 2; ++q) {
        const int rg = min(nb * 128 + q * 64 + srow, cnt - 1);
        const int arow = ((start + rg - 1) >> 1) + 1;
        gA[q] = (const unsigned*)(h_buf + (size_t)arow * HD + sslot * 8);
    }
    const unsigned short* gB[4];
    #pragma unroll
    for (int q = 0; q < 4; ++q) {
        const int r = q * 64 + srow;
        const int whrow = ((r >> 4) & 3) * 1024 + jg0 + ((r >> 6) * 16) + (r & 15);
        gB[q] = Whb + (size_t)whrow * HD + sslot * 8;
    }
    const int ldsoff = tid * 16;

    f32x4 acc[MR][4];
    #pragma unroll
    for (int i = 0; i < MR; ++i)
        #pragma unroll
        for (int j = 0; j < 4; ++j) { f32x4 z = {0.f, 0.f, 0.f, 0.f}; acc[i][j] = z; }

    // prologue: A(0) -> regs (MALL loads), B(0) -> LDS (normal path, L2-hot)
    unsigned aR[2][2][4];   // [tile parity][q][word] — all indices static
    #pragma unroll
    for (int q = 0; q < 2; ++q)
        #pragma unroll
        for (int w = 0; w < 4; ++w)
            aR[0][q][w] = mall_load_u32(gA[q] + w);
    #pragma unroll
    for (int q = 0; q < 4; ++q)
        gload_lds16(gB[q], ldsB + q * 8192 + ldsoff);

    #pragma unroll
    for (int t = 0; t < 16; ++t) {
        const char* LA = ldsA + (t & 1) * ABYTES;
        const char* LB = ldsB + (t & 1) * BBYTES;

        asm volatile("s_waitcnt vmcnt(0)" ::: "memory");  // A(t) regs + B(t) LDS
        __builtin_amdgcn_s_barrier();   // all waves done reading t-1 buffers

        // stage A(t) regs -> LDS (linear dest, source pre-swizzled)
        #pragma unroll
        for (int q = 0; q < 2; ++q)
            *(u32x4*)(ldsA + (t & 1) * ABYTES + q * 8192 + ldsoff) =
                *(const u32x4*)aR[t & 1][q];

        // prefetch A(t+1) regs + B(t+1) LDS
        if (t < 15) {
            #pragma unroll
            for (int q = 0; q < 2; ++q)
                #pragma unroll
                for (int w = 0; w < 4; ++w)
                    aR[(t + 1) & 1][q][w] = mall_load_u32(gA[q] + (t + 1) * 32 + w);
            #pragma unroll
            for (int q = 0; q < 4; ++q)
                gload_lds16(gB[q] + (t + 1) * 64,
                            ldsB + ((t + 1) & 1) * BBYTES + q * 8192 + ldsoff);
        }

        asm volatile("s_waitcnt lgkmcnt(0)" ::: "memory");
        __builtin_amdgcn_s_barrier();   // all ds_writes visible

        #pragma unroll
        for (int kk = 0; kk < 2; ++kk) {
            const int kbyte = kk * 64 + fq * 16;
            s16x8 aF[MR], bF[4];
            #pragma unroll
            for (int i = 0; i < MR; ++i) {
                const int row = wr * 64 + i * 16 + fr;
                aF[i] = *(const s16x8*)(LA + row * 128 + (kbyte ^ ((row & 7) << 4)));
            }
            #pragma unroll
            for (int j = 0; j < 4; ++j) {
                const int row = wc * 64 + j * 16 + fr;
                bF[j] = *(const s16x8*)(LB + row * 128 + (kbyte ^ ((row & 7) << 4)));
            }
            __builtin_amdgcn_s_setprio(1);
            #pragma unroll
            for (int i = 0; i < MR; ++i)
                #pragma unroll
                for (int j = 0; j < 4; ++j)
                    acc[i][j] = __builtin_amdgcn_mfma_f32_16x16x32_bf16(
                        aF[i], bF[j], acc[i][j], 0, 0, 0);
            __builtin_amdgcn_s_setprio(0);
        }
    }

    const int col = jg0 + wc * 16 + fr;
    #pragma unroll
    for (int i = 0; i < MR; ++i) {
        #pragma unroll
        for (int reg = 0; reg < 4; ++reg) {
            const int t = t0 + wr * 64 + i * 16 + fq * 4 + reg;
            if (t < lim) {
                const int prow = ((t - 1) >> 1) + 1;
                const size_t xb = (size_t)t * FH + col;
                union { unsigned u; float f; } cpv;
                cpv.u = mall_load_u32((const unsigned*)(c_buf + (size_t)prow * HD + col));
                const float gi = acc[i][0][reg] + __half2float(xproj[xb]);
                const float go = acc[i][1][reg] + __half2float(xproj[xb + HD]);
                const float gf = acc[i][2][reg] + __half2float(xproj[xb + 2 * HD]);
                const float gu = acc[i][3][reg] + __half2float(xproj[xb + 3 * HD]);
                const float c = fast_sig(gi) * fast_tanh(gu) + fast_sig(gf) * cpv.f;
                const float h = fast_sig(go) * fast_tanh(c);
                union { float f; unsigned u; } cv; cv.f = c;
                mall_store_u32((unsigned*)(c_buf + (size_t)(t + 1) * HD + col), cv.u);
                mall_store_u16(h_buf + (size_t)(t + 1) * HD + col, f2bf(h));
                out[(size_t)t * HD + col] = h;   // host-read only: plain store
            }
        }
    }

    // data stores ACK'd at MALL before flag add (no release flush needed)
    asm volatile("s_waitcnt vmcnt(0)" ::: "memory");
    __syncthreads();
    if (threadIdx.x == 0)
        __hip_atomic_fetch_add(done + lvl, 1, __ATOMIC_RELAXED,
                               __HIP_MEMORY_SCOPE_AGENT);
}

// ---------------------------------------------------------------------------
// Large levels (R9-proven): gather-free, BK=64, 2-buffer.
// ---------------------------------------------------------------------------
template<int BM>
__global__ __launch_bounds__(512, 2) void level_kk(
    const __half* __restrict__ xproj, const unsigned short* __restrict__ Whb,
    int start, int prevstart, unsigned short* __restrict__ h_buf,
    float* __restrict__ c_buf, float* __restrict__ out)
{
    constexpr int MR = BM / 32;
    constexpr int ABYTES = BM * 128;
    constexpr int BUF = ABYTES + 32768;
    __shared__ char lds[2 * BUF];
    const int tid = threadIdx.x;
    const int wid = tid >> 6, lane = tid & 63;
    const int wr = wid >> 2, wc = wid & 3;
    const int fr = lane & 15, fq = lane >> 4;
    const int t0 = start + blockIdx.x * BM;
    const int jg0 = blockIdx.y * 64;

    const int srow = tid >> 3;
    const int sslot = (tid & 7) ^ (srow & 7);
    const unsigned short* gA[BM / 64];
    #pragma unroll
    for (int q = 0; q < BM / 64; ++q) {
        const int rg = blockIdx.x * BM + q * 64 + srow;
        gA[q] = h_buf + (size_t)(prevstart + (rg >> 1) + 1) * HD + sslot * 8;
    }
    const unsigned short* gB[4];
    #pragma unroll
    for (int q = 0; q < 4; ++q) {
        const int r = q * 64 + srow;
        const int whrow = ((r >> 4) & 3) * 1024 + jg0 + ((r >> 6) * 16) + (r & 15);
        gB[q] = Whb + (size_t)whrow * HD + sslot * 8;
    }
    const int ldsoff = tid * 16;

    f32x4 acc[MR][4];
    #pragma unroll
    for (int i = 0; i < MR; ++i)
        #pragma unroll
        for (int j = 0; j < 4; ++j) { f32x4 z = {0.f, 0.f, 0.f, 0.f}; acc[i][j] = z; }

    #pragma unroll
    for (int q = 0; q < BM / 64; ++q)
        gload_lds16(gA[q], lds + q * 8192 + ldsoff);
    #pragma unroll
    for (int q = 0; q < 4; ++q)
        gload_lds16(gB[q], lds + ABYTES + q * 8192 + ldsoff);

    for (int t = 0; t < 16; ++t) {
        const char* LA = lds + (t & 1) * BUF;
        const char* LB = LA + ABYTES;
        char* SA = lds + ((t & 1) ^ 1) * BUF;
        char* SB = SA + ABYTES;
        const int knext = (t + 1) * 64;

        asm volatile("s_waitcnt vmcnt(0)" ::: "memory");
        __builtin_amdgcn_s_barrier();

        #pragma unroll
        for (int kk = 0; kk < 2; ++kk) {
            const int kbyte = kk * 64 + fq * 16;
            s16x8 aF[MR], bF[4];
            #pragma unroll
            for (int i = 0; i < MR; ++i) {
                const int row = wr * (BM / 2) + i * 16 + fr;
                aF[i] = *(const s16x8*)(LA + row * 128 + (kbyte ^ ((row & 7) << 4)));
            }
            #pragma unroll
            for (int j = 0; j < 4; ++j) {
                const int row = wc * 64 + j * 16 + fr;
                bF[j] = *(const s16x8*)(LB + row * 128 + (kbyte ^ ((row & 7) << 4)));
            }
            if (t < 15) {
                if (kk == 0) {
                    #pragma unroll
                    for (int q = 0; q < BM / 64; ++q)
                        gload_lds16(gA[q] + knext, SA + q * 8192 + ldsoff);
                } else {
                    #pragma unroll
                    for (int q = 0; q < 4; ++q)
                        gload_lds16(gB[q] + knext, SB + q * 8192 + ldsoff);
                }
            }
            __builtin_amdgcn_s_setprio(1);
            #pragma unroll
            for (int i = 0; i < MR; ++i)
                #pragma unroll
                for (int j = 0; j < 4; ++j)
                    acc[i][j] = __builtin_amdgcn_mfma_f32_16x16x32_bf16(
                        aF[i], bF[j], acc[i][j], 0, 0, 0);
            __builtin_amdgcn_s_setprio(0);
        }
    }

    const int col = jg0 + wc * 16 + fr;
    #pragma unroll
    for (int i = 0; i < MR; ++i) {
        #pragma unroll
        for (int reg = 0; reg < 4; ++reg) {
            const int t = t0 + wr * (BM / 2) + i * 16 + fq * 4 + reg;
            const int p = (t - 1) >> 1;
            const size_t xb = (size_t)t * FH + col;
            const float gi = acc[i][0][reg] + __half2float(xproj[xb]);
            const float go = acc[i][1][reg] + __half2float(xproj[xb + HD]);
            const float gf = acc[i][2][reg] + __half2float(xproj[xb + 2 * HD]);
            const float gu = acc[i][3][reg] + __half2float(xproj[xb + 3 * HD]);
            const float cp = c_buf[(size_t)(p + 1) * HD + col];
            const float c = fast_sig(gi) * fast_tanh(gu) + fast_sig(gf) * cp;
            const float h = fast_sig(go) * fast_tanh(c);
            c_buf[(size_t)(t + 1) * HD + col] = c;
            h_buf[(size_t)(t + 1) * HD + col] = f2bf(h);
            out[(size_t)t * HD + col] = h;
        }
    }
}

// ---------------------------------------------------------------------------
// Straggler (node 8191): BK=128 dbuf kernel (R5-proven), parent[] path
// ---------------------------------------------------------------------------
__device__ __forceinline__ void bk128_issue(
    const unsigned short* const (&gA)[8], const unsigned short* const (&gB)[8],
    int k0, unsigned short* As, unsigned short* Bs, int wbase)
{
    #pragma unroll
    for (int q = 0; q < 8; ++q) {
        gload_lds16(gA[q] + k0, (char*)As + q * 4096 + wbase);
        gload_lds16(gB[q] + k0, (char*)Bs + q * 4096 + wbase);
    }
}

__device__ __forceinline__ void bk128_compute(
    const unsigned short* As, const unsigned short* Bs,
    f32x4 (&acc)[4][4], int wm, int wn16, int fr, int fkb)
{
    #pragma unroll
    for (int kk = 0; kk < 4; ++kk) {
        s16x8 aF[4], bF[4];
        #pragma unroll
        for (int i = 0; i < 4; ++i) {
            const int r = wm + i * 16 + fr;
            const int byteIn = (kk * 64 + fkb) ^ ((r & 7) << 4);
            aF[i] = *(const s16x8*)((const char*)As + r * 256 + byteIn);
        }
        #pragma unroll
        for (int g = 0; g < 4; ++g) {
            const int r = g * 32 + wn16 + fr;
            const int byteIn = (kk * 64 + fkb) ^ ((r & 7) << 4);
            bF[g] = *(const s16x8*)((const char*)Bs + r * 256 + byteIn);
        }
        #pragma unroll
        for (int i = 0; i < 4; ++i)
            #pragma unroll
            for (int g = 0; g < 4; ++g)
                acc[i][g] = __builtin_amdgcn_mfma_f32_16x16x32_bf16(aF[i], bF[g], acc[i][g], 0, 0, 0);
    }
}

__global__ __launch_bounds__(256) void level_bk128_dbuf(
    const __half* __restrict__ xproj, const unsigned short* __restrict__ Whb,
    const int* __restrict__ parent, unsigned short* __restrict__ h_buf,
    float* __restrict__ c_buf, float* __restrict__ out,
    int start, int count)
{
    __shared__ unsigned short As0[128 * 128];
    __shared__ unsigned short Bs0[128 * 128];
    __shared__ unsigned short As1[128 * 128];
    __shared__ unsigned short Bs1[128 * 128];
    const int tid = threadIdx.x;
    const int wid = tid >> 6;
    const int lane = tid & 63;
    const int t0 = start + blockIdx.x * 128;
    const int jg0 = blockIdx.y * 32;
    const int lim = start + count;
    const int wm = (wid & 1) * 64;
    const int wn16 = (wid >> 1) * 16;
    const int wbase = wid * 1024;
    const int srow_b = tid >> 4;
    const int rowbyte = (tid & 15) * 16;

    const unsigned short* gA[8];
    const unsigned short* gB[8];
    #pragma unroll
    for (int q = 0; q < 8; ++q) {
        const int r = q * 16 + srow_b;
        const int sk = (rowbyte ^ ((r & 7) << 4)) >> 1;
        const int tA = min(t0 + r, lim - 1);
        gA[q] = h_buf + (size_t)(parent[tA] + 1) * HD + sk;
        const int whrow = ((r >> 5) << 10) + jg0 + (r & 31);
        gB[q] = Whb + (size_t)whrow * HD + sk;
    }

    f32x4 acc[4][4];
    #pragma unroll
    for (int i = 0; i < 4; ++i)
        #pragma unroll
        for (int g = 0; g < 4; ++g) { f32x4 z = {0.f, 0.f, 0.f, 0.f}; acc[i][g] = z; }

    const int fr = lane & 15;
    const int fkb = (lane >> 4) * 16;

    bk128_issue(gA, gB, 0, As0, Bs0, wbase);
    #pragma unroll
    for (int t = 0; t < 8; ++t) {
        unsigned short* curA = (t & 1) ? As1 : As0;
        unsigned short* curB = (t & 1) ? Bs1 : Bs0;
        unsigned short* nxtA = (t & 1) ? As0 : As1;
        unsigned short* nxtB = (t & 1) ? Bs0 : Bs1;
        if (t < 7) {
            bk128_issue(gA, gB, (t + 1) * 128, nxtA, nxtB, wbase);
            asm volatile("s_waitcnt vmcnt(16)" ::: "memory");
        } else {
            asm volatile("s_waitcnt vmcnt(0)" ::: "memory");
        }
        __builtin_amdgcn_s_barrier();
        __builtin_amdgcn_sched_barrier(0);
        bk128_compute(curA, curB, acc, wm, wn16, fr, fkb);
        __builtin_amdgcn_sched_barrier(0);
        __builtin_amdgcn_s_barrier();
    }

    const int col = jg0 + wn16 + fr;
    const int fq = lane >> 4;
    #pragma unroll
    for (int i = 0; i < 4; ++i) {
        #pragma unroll
        for (int reg = 0; reg < 4; ++reg) {
            const int t = t0 + wm + i * 16 + fq * 4 + reg;
            if (t < lim) {
                const int p = parent[t];
                const size_t xb = (size_t)t * FH + col;
                const float gi = acc[i][0][reg] + __half2float(xproj[xb]);
                const float go = acc[i][1][reg] + __half2float(xproj[xb + HD]);
                const float gf = acc[i][2][reg] + __half2float(xproj[xb + 2 * HD]);
                const float gu = acc[i][3][reg] + __half2float(xproj[xb + 3 * HD]);
                const float cp = c_buf[(size_t)(p + 1) * HD + col];
                const float c = fast_sig(gi) * fast_tanh(gu) + fast_sig(gf) * cp;
                const float h = fast_sig(go) * fast_tanh(c);
                c_buf[(size_t)(t + 1) * HD + col] = c;
                h_buf[(size_t)(t + 1) * HD + col] = f2bf(h);
                out[(size_t)t * HD + col] = h;
            }
        }
    }
}

extern "C" void kernel_launch(void* const* d_in, const int* in_sizes, int n_in,
                              void* d_out, int out_size, void* d_ws, size_t ws_size,
                              hipStream_t stream) {
    const float* feat   = (const float*)d_in[0];
    const float* Wx     = (const float*)d_in[1];
    const float* bx     = (const float*)d_in[2];
    const float* Wh     = (const float*)d_in[3];
    const float* bh     = (const float*)d_in[4];
    const int*   parent = (const int*)d_in[5];
    const float* root_c = (const float*)d_in[6];
    const float* root_h = (const float*)d_in[7];
    float* out = (float*)d_out;

    char* ws = (char*)d_ws;
    __half* xproj = (__half*)ws;                        ws += (size_t)NN * FH * 2;
    float* c_buf = (float*)ws;                          ws += (size_t)(NN + 1) * HD * 4;
    unsigned short* feat_b = (unsigned short*)ws;       ws += (size_t)NN * FEAT * 2;
    unsigned short* Wx_b = (unsigned short*)ws;         ws += (size_t)FH * FEAT * 2;
    unsigned short* Wh_b = (unsigned short*)ws;         ws += (size_t)FH * HD * 2;
    unsigned short* h_buf = (unsigned short*)ws;        ws += (size_t)(NN + 1) * HD * 2;
    int* done = (int*)ws;                               ws += 256;

    const size_t ntot = (size_t)NN * FEAT + (size_t)FH * FEAT + (size_t)FH * HD;
    convert_all_kernel<<<(unsigned)(ntot / 8 / 256), 256, 0, stream>>>(
        feat, Wx, Wh, feat_b, Wx_b, Wh_b, root_h, root_c, h_buf, c_buf, done);

    dim3 g1(NN / 256, FH / 256);
    xproj_8ph<<<g1, 512, 0, stream>>>(feat_b, Wx_b, bx, bh, xproj);

    // levels 0..9 (nodes 0..1022) in ONE launch, fence-free MALL protocol
    levels_fused_small<<<224, 512, 0, stream>>>(
        xproj, Wh_b, h_buf, c_buf, out, done);

    // large levels: gather-free kk-split (R9-proven), 256 blocks each
    dim3 gl(16, 16);
    level_kk<64><<<gl, 512, 0, stream>>>(xproj, Wh_b, 1023, 511,
                                         h_buf, c_buf, out);
    level_kk<128><<<gl, 512, 0, stream>>>(xproj, Wh_b, 2047, 1023,
                                          h_buf, c_buf, out);
    level_kk<256><<<gl, 512, 0, stream>>>(xproj, Wh_b, 4095, 2047,
                                          h_buf, c_buf, out);

    // straggler node 8191 (parent 4095)
    dim3 g3(1, HD / 32);
    level_bk128_dbuf<<<g3, 256, 0, stream>>>(
        xproj, Wh_b, parent, h_buf, c_buf, out, 8191, 1);
}

// Round 17
// 456.461 us; speedup vs baseline: 1.1986x; 1.1986x over previous
//
#include <hip/hip_runtime.h>
#include <hip/hip_fp16.h>
#include <math.h>

#define FEAT 2048
#define HD 1024
#define FH 4096
#define NN 8192

using s16x8 = __attribute__((ext_vector_type(8))) short;
using f32x4 = __attribute__((ext_vector_type(4))) float;

#define GLOBAL_AS __attribute__((address_space(1)))
#define LDS_AS __attribute__((address_space(3)))

__device__ __forceinline__ void gload_lds16(const void* g, void* l) {
    __builtin_amdgcn_global_load_lds((const GLOBAL_AS unsigned int*)g,
                                     (LDS_AS unsigned int*)l, 16, 0, 0);
}

__device__ __forceinline__ unsigned short f2bf(float f) {
    union { float f; unsigned u; } v; v.f = f;
    unsigned r = v.u + 0x7FFFu + ((v.u >> 16) & 1u);  // RNE
    return (unsigned short)(r >> 16);
}

__device__ __forceinline__ float fast_sig(float x) { return 1.0f / (1.0f + __expf(-x)); }
__device__ __forceinline__ float fast_tanh(float x) {
    float ax = fabsf(x);
    float e = __expf(2.0f * ax);
    float r = 1.0f - 2.0f / (e + 1.0f);
    return copysignf(r, x);
}

// ---------------------------------------------------------------------------
// fused fp32 -> bf16 convert for feat, Wx, Wh  (+ root h/c init + flag reset)
// ---------------------------------------------------------------------------
__global__ __launch_bounds__(256) void convert_all_kernel(
    const float* __restrict__ feat, const float* __restrict__ Wx,
    const float* __restrict__ Wh, unsigned short* __restrict__ feat_b,
    unsigned short* __restrict__ Wx_b, unsigned short* __restrict__ Wh_b,
    const float* __restrict__ root_h, const float* __restrict__ root_c,
    unsigned short* __restrict__ h_buf, float* __restrict__ c_buf,
    int* __restrict__ done)
{
    const size_t g = (size_t)blockIdx.x * 256 + threadIdx.x;
    if (g < HD) { h_buf[g] = f2bf(root_h[g]); c_buf[g] = root_c[g]; }
    if (g < 16) done[g] = 0;

    const size_t n1 = (size_t)NN * FEAT;
    const size_t n2 = n1 + (size_t)FH * FEAT;
    size_t i = g * 8;
    const float* s; unsigned short* d;
    if (i < n1)      { s = feat + i;        d = feat_b + i; }
    else if (i < n2) { s = Wx + (i - n1);   d = Wx_b + (i - n1); }
    else             { s = Wh + (i - n2);   d = Wh_b + (i - n2); }
    float4 a = *(const float4*)s;
    float4 b = *(const float4*)(s + 4);
    unsigned short r[8] = {f2bf(a.x), f2bf(a.y), f2bf(a.z), f2bf(a.w),
                           f2bf(b.x), f2bf(b.y), f2bf(b.z), f2bf(b.w)};
    *(s16x8*)d = *(const s16x8*)r;
}

// ---------------------------------------------------------------------------
// xproj = feat @ Wx^T + (bx+bh). 256x256 BK=64 kk-split (R7 schedule),
// fp16 output via LDS repack (R13-proven full-sector stores).
// ---------------------------------------------------------------------------
__global__ __launch_bounds__(512, 2) void xproj_8ph(
    const unsigned short* __restrict__ Ab,
    const unsigned short* __restrict__ Bb,
    const float* __restrict__ bx, const float* __restrict__ bh,
    __half* __restrict__ xproj)
{
    __shared__ char lds[131072];
    const int tid = threadIdx.x;
    const int wid = tid >> 6;
    const int lane = tid & 63;
    const int wr = wid >> 2;
    const int wc = wid & 3;
    const int bm = blockIdx.x * 256;
    const int bn = blockIdx.y * 256;
    const int fr = lane & 15;
    const int fq = lane >> 4;

    const int srow = tid >> 3;
    const int sslot = (tid & 7) ^ (srow & 7);
    const unsigned short* gA[4];
    const unsigned short* gB[4];
    #pragma unroll
    for (int q = 0; q < 4; ++q) {
        gA[q] = Ab + (size_t)(bm + q * 64 + srow) * FEAT + sslot * 8;
        gB[q] = Bb + (size_t)(bn + q * 64 + srow) * FEAT + sslot * 8;
    }
    const int ldsoff = tid * 16;

    f32x4 acc[8][4];
    #pragma unroll
    for (int i = 0; i < 8; ++i)
        #pragma unroll
        for (int j = 0; j < 4; ++j) { f32x4 z = {0.f, 0.f, 0.f, 0.f}; acc[i][j] = z; }

    #pragma unroll
    for (int q = 0; q < 4; ++q) {
        gload_lds16(gA[q], lds + q * 8192 + ldsoff);
        gload_lds16(gB[q], lds + 32768 + q * 8192 + ldsoff);
    }

    for (int t = 0; t < 32; ++t) {
        const int d = t & 1;
        const char* LA = lds + d * 65536;
        const char* LB = LA + 32768;
        char* SA = lds + (d ^ 1) * 65536;
        char* SB = SA + 32768;
        const int knext = (t + 1) * 64;

        asm volatile("s_waitcnt vmcnt(0)" ::: "memory");
        __builtin_amdgcn_s_barrier();

        #pragma unroll
        for (int kk = 0; kk < 2; ++kk) {
            const int kbyte = kk * 64 + fq * 16;
            s16x8 aF[8], bF[4];
            #pragma unroll
            for (int i = 0; i < 8; ++i) {
                const int row = wr * 128 + i * 16 + fr;
                aF[i] = *(const s16x8*)(LA + row * 128 + (kbyte ^ ((row & 7) << 4)));
            }
            #pragma unroll
            for (int j = 0; j < 4; ++j) {
                const int row = wc * 64 + j * 16 + fr;
                bF[j] = *(const s16x8*)(LB + row * 128 + (kbyte ^ ((row & 7) << 4)));
            }
            if (t < 31) {
                if (kk == 0) {
                    #pragma unroll
                    for (int q = 0; q < 4; ++q)
                        gload_lds16(gA[q] + knext, SA + q * 8192 + ldsoff);
                } else {
                    #pragma unroll
                    for (int q = 0; q < 4; ++q)
                        gload_lds16(gB[q] + knext, SB + q * 8192 + ldsoff);
                }
            }
            __builtin_amdgcn_s_setprio(1);
            #pragma unroll
            for (int i = 0; i < 8; ++i)
                #pragma unroll
                for (int j = 0; j < 4; ++j)
                    acc[i][j] = __builtin_amdgcn_mfma_f32_16x16x32_bf16(
                        aF[i], bF[j], acc[i][j], 0, 0, 0);
            __builtin_amdgcn_s_setprio(0);
        }
    }

    // ---- epilogue: LDS repack to coalesced fp16 stores (R13) ----
    __builtin_amdgcn_s_barrier();
    char* W = lds + wid * 16384;
    #pragma unroll
    for (int j = 0; j < 4; ++j) {
        const int c_loc = j * 16 + fr;
        const int col = bn + wc * 64 + c_loc;
        const float bias = bx[col] + bh[col];
        #pragma unroll
        for (int i = 0; i < 8; ++i) {
            #pragma unroll
            for (int reg = 0; reg < 4; ++reg) {
                const int r_loc = i * 16 + fq * 4 + reg;
                const int byteo = r_loc * 128 +
                    ((((c_loc >> 3) ^ (r_loc & 7)) << 4)) + (c_loc & 7) * 2;
                *(__half*)(W + byteo) = __float2half_rn(acc[i][j][reg] + bias);
            }
        }
    }
    asm volatile("s_waitcnt lgkmcnt(0)" ::: "memory");
    #pragma unroll
    for (int k = 0; k < 16; ++k) {
        const int f = k * 64 + lane;
        const int r_loc = f >> 3;
        const int cchunk = f & 7;
        const s16x8 v = *(const s16x8*)(W + r_loc * 128 +
                                        ((cchunk ^ (r_loc & 7)) << 4));
        const int grow = bm + wr * 128 + r_loc;
        const int gcol = bn + wc * 64 + cchunk * 8;
        *(s16x8*)((unsigned short*)xproj + (size_t)grow * FH + gcol) = v;
    }
}

// ---------------------------------------------------------------------------
// Levels 0..9 fused (R15 protocol: relaxed poll + one acquire fence, release
// flag add). NEW vs R15: the block's B(0) tile (read-only Wh — needs no
// ordering) is staged into LDS BEFORE the poll, so its HBM latency hides
// under the wait and the post-fence critical path is only the dependent
// A/c loads. Cache invalidation does not touch LDS. 224 blocks x 96 KB.
// ---------------------------------------------------------------------------
__global__ __launch_bounds__(512, 2) void levels_fused_small(
    const __half* __restrict__ xproj, const unsigned short* __restrict__ Whb,
    unsigned short* __restrict__ h_buf, float* __restrict__ c_buf,
    float* __restrict__ out, int* __restrict__ done)
{
    constexpr int MR = 4;
    constexpr int ABYTES = 128 * 128;     // 16 KB per A buffer
    constexpr int BBYTES = 32768;         // 32 KB per B buffer
    __shared__ char ldsA[2 * ABYTES];     // 32 KB
    __shared__ char ldsB[2 * BBYTES];     // 64 KB
    const int bid = blockIdx.x;
    int lvl, nb;
    if (bid < 128)      { lvl = bid >> 4; nb = 0; }
    else if (bid < 160) { lvl = 8;        nb = (bid - 128) >> 4; }
    else                { lvl = 9;        nb = (bid - 160) >> 4; }
    const int jg0 = (bid & 15) * 64;
    const int start = (1 << lvl) - 1;
    const int cnt = 1 << lvl;
    const int lim = start + cnt;
    const int t0 = start + nb * 128;

    const int tid = threadIdx.x;
    const int wid = tid >> 6, lane = tid & 63;
    const int wr = wid >> 2, wc = wid & 3;
    const int fr = lane & 15, fq = lane >> 4;

    const int srow = tid >> 3;
    const int sslot = (tid & 7) ^ (srow & 7);
    const unsigned short* gA[2];
    #pragma unroll
    for (int q = 0; q < 2; ++q) {
        const int rg = min(nb * 128 + q * 64 + srow, cnt - 1);
        const int arow = ((start + rg - 1) >> 1) + 1;
        gA[q] = h_buf + (size_t)arow * HD + sslot * 8;
    }
    const unsigned short* gB[4];
    #pragma unroll
    for (int q = 0; q < 4; ++q) {
        const int r = q * 64 + srow;
        const int whrow = ((r >> 4) & 3) * 1024 + jg0 + ((r >> 6) * 16) + (r & 15);
        gB[q] = Whb + (size_t)whrow * HD + sslot * 8;
    }
    const int ldsoff = tid * 16;

    // PRE-POLL: stage B(0) — read-only data, no ordering needed; completes
    // while this block waits for its level.
    #pragma unroll
    for (int q = 0; q < 4; ++q)
        gload_lds16(gB[q], ldsB + q * 8192 + ldsoff);

    // wait for previous level: relaxed poll (no per-poll invalidate), then
    // ONE acquire fence (invL2) — LDS contents unaffected.
    if (lvl > 0) {
        if (threadIdx.x == 0) {
            const int need = (lvl <= 8) ? 16 : 32;   // nblk[lvl-1]
            while (__hip_atomic_load(done + (lvl - 1), __ATOMIC_RELAXED,
                                     __HIP_MEMORY_SCOPE_AGENT) < need)
                __builtin_amdgcn_s_sleep(4);
        }
        __syncthreads();
        __builtin_amdgcn_fence(__ATOMIC_ACQUIRE, "agent");
    }

    f32x4 acc[MR][4];
    #pragma unroll
    for (int i = 0; i < MR; ++i)
        #pragma unroll
        for (int j = 0; j < 4; ++j) { f32x4 z = {0.f, 0.f, 0.f, 0.f}; acc[i][j] = z; }

    // post-fence: stage A(0) (dependent data)
    #pragma unroll
    for (int q = 0; q < 2; ++q)
        gload_lds16(gA[q], ldsA + q * 8192 + ldsoff);

    for (int t = 0; t < 16; ++t) {
        const char* LA = ldsA + (t & 1) * ABYTES;
        const char* LB = ldsB + (t & 1) * BBYTES;
        char* SA = ldsA + ((t & 1) ^ 1) * ABYTES;
        char* SB = ldsB + ((t & 1) ^ 1) * BBYTES;
        const int knext = (t + 1) * 64;

        asm volatile("s_waitcnt vmcnt(0)" ::: "memory");
        __builtin_amdgcn_s_barrier();

        #pragma unroll
        for (int kk = 0; kk < 2; ++kk) {
            const int kbyte = kk * 64 + fq * 16;
            s16x8 aF[MR], bF[4];
            #pragma unroll
            for (int i = 0; i < MR; ++i) {
                const int row = wr * 64 + i * 16 + fr;
                aF[i] = *(const s16x8*)(LA + row * 128 + (kbyte ^ ((row & 7) << 4)));
            }
            #pragma unroll
            for (int j = 0; j < 4; ++j) {
                const int row = wc * 64 + j * 16 + fr;
                bF[j] = *(const s16x8*)(LB + row * 128 + (kbyte ^ ((row & 7) << 4)));
            }
            if (t < 15) {
                if (kk == 0) {
                    #pragma unroll
                    for (int q = 0; q < 2; ++q)
                        gload_lds16(gA[q] + knext, SA + q * 8192 + ldsoff);
                } else {
                    #pragma unroll
                    for (int q = 0; q < 4; ++q)
                        gload_lds16(gB[q] + knext, SB + q * 8192 + ldsoff);
                }
            }
            __builtin_amdgcn_s_setprio(1);
            #pragma unroll
            for (int i = 0; i < MR; ++i)
                #pragma unroll
                for (int j = 0; j < 4; ++j)
                    acc[i][j] = __builtin_amdgcn_mfma_f32_16x16x32_bf16(
                        aF[i], bF[j], acc[i][j], 0, 0, 0);
            __builtin_amdgcn_s_setprio(0);
        }
    }

    const int col = jg0 + wc * 16 + fr;
    #pragma unroll
    for (int i = 0; i < MR; ++i) {
        #pragma unroll
        for (int reg = 0; reg < 4; ++reg) {
            const int t = t0 + wr * 64 + i * 16 + fq * 4 + reg;
            if (t < lim) {
                const int prow = ((t - 1) >> 1) + 1;
                const size_t xb = (size_t)t * FH + col;
                const float gi = acc[i][0][reg] + __half2float(xproj[xb]);
                const float go = acc[i][1][reg] + __half2float(xproj[xb + HD]);
                const float gf = acc[i][2][reg] + __half2float(xproj[xb + 2 * HD]);
                const float gu = acc[i][3][reg] + __half2float(xproj[xb + 3 * HD]);
                const float cp = c_buf[(size_t)prow * HD + col];
                const float c = fast_sig(gi) * fast_tanh(gu) + fast_sig(gf) * cp;
                const float h = fast_sig(go) * fast_tanh(c);
                c_buf[(size_t)(t + 1) * HD + col] = c;
                h_buf[(size_t)(t + 1) * HD + col] = f2bf(h);
                out[(size_t)t * HD + col] = h;
            }
        }
    }

    // signal level completion (release: wbL2 once per block)
    __syncthreads();
    if (threadIdx.x == 0)
        __hip_atomic_fetch_add(done + lvl, 1, __ATOMIC_RELEASE,
                               __HIP_MEMORY_SCOPE_AGENT);
}

// ---------------------------------------------------------------------------
// Large levels (R9-proven): gather-free, BK=64, 2-buffer.
// ---------------------------------------------------------------------------
template<int BM>
__global__ __launch_bounds__(512, 2) void level_kk(
    const __half* __restrict__ xproj, const unsigned short* __restrict__ Whb,
    int start, int prevstart, unsigned short* __restrict__ h_buf,
    float* __restrict__ c_buf, float* __restrict__ out)
{
    constexpr int MR = BM / 32;
    constexpr int ABYTES = BM * 128;
    constexpr int BUF = ABYTES + 32768;
    __shared__ char lds[2 * BUF];
    const int tid = threadIdx.x;
    const int wid = tid >> 6, lane = tid & 63;
    const int wr = wid >> 2, wc = wid & 3;
    const int fr = lane & 15, fq = lane >> 4;
    const int t0 = start + blockIdx.x * BM;
    const int jg0 = blockIdx.y * 64;

    const int srow = tid >> 3;
    const int sslot = (tid & 7) ^ (srow & 7);
    const unsigned short* gA[BM / 64];
    #pragma unroll
    for (int q = 0; q < BM / 64; ++q) {
        const int rg = blockIdx.x * BM + q * 64 + srow;
        gA[q] = h_buf + (size_t)(prevstart + (rg >> 1) + 1) * HD + sslot * 8;
    }
    const unsigned short* gB[4];
    #pragma unroll
    for (int q = 0; q < 4; ++q) {
        const int r = q * 64 + srow;
        const int whrow = ((r >> 4) & 3) * 1024 + jg0 + ((r >> 6) * 16) + (r & 15);
        gB[q] = Whb + (size_t)whrow * HD + sslot * 8;
    }
    const int ldsoff = tid * 16;

    f32x4 acc[MR][4];
    #pragma unroll
    for (int i = 0; i < MR; ++i)
        #pragma unroll
        for (int j = 0; j < 4; ++j) { f32x4 z = {0.f, 0.f, 0.f, 0.f}; acc[i][j] = z; }

    #pragma unroll
    for (int q = 0; q < BM / 64; ++q)
        gload_lds16(gA[q], lds + q * 8192 + ldsoff);
    #pragma unroll
    for (int q = 0; q < 4; ++q)
        gload_lds16(gB[q], lds + ABYTES + q * 8192 + ldsoff);

    for (int t = 0; t < 16; ++t) {
        const char* LA = lds + (t & 1) * BUF;
        const char* LB = LA + ABYTES;
        char* SA = lds + ((t & 1) ^ 1) * BUF;
        char* SB = SA + ABYTES;
        const int knext = (t + 1) * 64;

        asm volatile("s_waitcnt vmcnt(0)" ::: "memory");
        __builtin_amdgcn_s_barrier();

        #pragma unroll
        for (int kk = 0; kk < 2; ++kk) {
            const int kbyte = kk * 64 + fq * 16;
            s16x8 aF[MR], bF[4];
            #pragma unroll
            for (int i = 0; i < MR; ++i) {
                const int row = wr * (BM / 2) + i * 16 + fr;
                aF[i] = *(const s16x8*)(LA + row * 128 + (kbyte ^ ((row & 7) << 4)));
            }
            #pragma unroll
            for (int j = 0; j < 4; ++j) {
                const int row = wc * 64 + j * 16 + fr;
                bF[j] = *(const s16x8*)(LB + row * 128 + (kbyte ^ ((row & 7) << 4)));
            }
            if (t < 15) {
                if (kk == 0) {
                    #pragma unroll
                    for (int q = 0; q < BM / 64; ++q)
                        gload_lds16(gA[q] + knext, SA + q * 8192 + ldsoff);
                } else {
                    #pragma unroll
                    for (int q = 0; q < 4; ++q)
                        gload_lds16(gB[q] + knext, SB + q * 8192 + ldsoff);
                }
            }
            __builtin_amdgcn_s_setprio(1);
            #pragma unroll
            for (int i = 0; i < MR; ++i)
                #pragma unroll
                for (int j = 0; j < 4; ++j)
                    acc[i][j] = __builtin_amdgcn_mfma_f32_16x16x32_bf16(
                        aF[i], bF[j], acc[i][j], 0, 0, 0);
            __builtin_amdgcn_s_setprio(0);
        }
    }

    const int col = jg0 + wc * 16 + fr;
    #pragma unroll
    for (int i = 0; i < MR; ++i) {
        #pragma unroll
        for (int reg = 0; reg < 4; ++reg) {
            const int t = t0 + wr * (BM / 2) + i * 16 + fq * 4 + reg;
            const int p = (t - 1) >> 1;
            const size_t xb = (size_t)t * FH + col;
            const float gi = acc[i][0][reg] + __half2float(xproj[xb]);
            const float go = acc[i][1][reg] + __half2float(xproj[xb + HD]);
            const float gf = acc[i][2][reg] + __half2float(xproj[xb + 2 * HD]);
            const float gu = acc[i][3][reg] + __half2float(xproj[xb + 3 * HD]);
            const float cp = c_buf[(size_t)(p + 1) * HD + col];
            const float c = fast_sig(gi) * fast_tanh(gu) + fast_sig(gf) * cp;
            const float h = fast_sig(go) * fast_tanh(c);
            c_buf[(size_t)(t + 1) * HD + col] = c;
            h_buf[(size_t)(t + 1) * HD + col] = f2bf(h);
            out[(size_t)t * HD + col] = h;
        }
    }
}

// ---------------------------------------------------------------------------
// Straggler (node 8191): BK=128 dbuf kernel (R5-proven), parent[] path
// ---------------------------------------------------------------------------
__device__ __forceinline__ void bk128_issue(
    const unsigned short* const (&gA)[8], const unsigned short* const (&gB)[8],
    int k0, unsigned short* As, unsigned short* Bs, int wbase)
{
    #pragma unroll
    for (int q = 0; q < 8; ++q) {
        gload_lds16(gA[q] + k0, (char*)As + q * 4096 + wbase);
        gload_lds16(gB[q] + k0, (char*)Bs + q * 4096 + wbase);
    }
}

__device__ __forceinline__ void bk128_compute(
    const unsigned short* As, const unsigned short* Bs,
    f32x4 (&acc)[4][4], int wm, int wn16, int fr, int fkb)
{
    #pragma unroll
    for (int kk = 0; kk < 4; ++kk) {
        s16x8 aF[4], bF[4];
        #pragma unroll
        for (int i = 0; i < 4; ++i) {
            const int r = wm + i * 16 + fr;
            const int byteIn = (kk * 64 + fkb) ^ ((r & 7) << 4);
            aF[i] = *(const s16x8*)((const char*)As + r * 256 + byteIn);
        }
        #pragma unroll
        for (int g = 0; g < 4; ++g) {
            const int r = g * 32 + wn16 + fr;
            const int byteIn = (kk * 64 + fkb) ^ ((r & 7) << 4);
            bF[g] = *(const s16x8*)((const char*)Bs + r * 256 + byteIn);
        }
        #pragma unroll
        for (int i = 0; i < 4; ++i)
            #pragma unroll
            for (int g = 0; g < 4; ++g)
                acc[i][g] = __builtin_amdgcn_mfma_f32_16x16x32_bf16(aF[i], bF[g], acc[i][g], 0, 0, 0);
    }
}

__global__ __launch_bounds__(256) void level_bk128_dbuf(
    const __half* __restrict__ xproj, const unsigned short* __restrict__ Whb,
    const int* __restrict__ parent, unsigned short* __restrict__ h_buf,
    float* __restrict__ c_buf, float* __restrict__ out,
    int start, int count)
{
    __shared__ unsigned short As0[128 * 128];
    __shared__ unsigned short Bs0[128 * 128];
    __shared__ unsigned short As1[128 * 128];
    __shared__ unsigned short Bs1[128 * 128];
    const int tid = threadIdx.x;
    const int wid = tid >> 6;
    const int lane = tid & 63;
    const int t0 = start + blockIdx.x * 128;
    const int jg0 = blockIdx.y * 32;
    const int lim = start + count;
    const int wm = (wid & 1) * 64;
    const int wn16 = (wid >> 1) * 16;
    const int wbase = wid * 1024;
    const int srow_b = tid >> 4;
    const int rowbyte = (tid & 15) * 16;

    const unsigned short* gA[8];
    const unsigned short* gB[8];
    #pragma unroll
    for (int q = 0; q < 8; ++q) {
        const int r = q * 16 + srow_b;
        const int sk = (rowbyte ^ ((r & 7) << 4)) >> 1;
        const int tA = min(t0 + r, lim - 1);
        gA[q] = h_buf + (size_t)(parent[tA] + 1) * HD + sk;
        const int whrow = ((r >> 5) << 10) + jg0 + (r & 31);
        gB[q] = Whb + (size_t)whrow * HD + sk;
    }

    f32x4 acc[4][4];
    #pragma unroll
    for (int i = 0; i < 4; ++i)
        #pragma unroll
        for (int g = 0; g < 4; ++g) { f32x4 z = {0.f, 0.f, 0.f, 0.f}; acc[i][g] = z; }

    const int fr = lane & 15;
    const int fkb = (lane >> 4) * 16;

    bk128_issue(gA, gB, 0, As0, Bs0, wbase);
    #pragma unroll
    for (int t = 0; t < 8; ++t) {
        unsigned short* curA = (t & 1) ? As1 : As0;
        unsigned short* curB = (t & 1) ? Bs1 : Bs0;
        unsigned short* nxtA = (t & 1) ? As0 : As1;
        unsigned short* nxtB = (t & 1) ? Bs0 : Bs1;
        if (t < 7) {
            bk128_issue(gA, gB, (t + 1) * 128, nxtA, nxtB, wbase);
            asm volatile("s_waitcnt vmcnt(16)" ::: "memory");
        } else {
            asm volatile("s_waitcnt vmcnt(0)" ::: "memory");
        }
        __builtin_amdgcn_s_barrier();
        __builtin_amdgcn_sched_barrier(0);
        bk128_compute(curA, curB, acc, wm, wn16, fr, fkb);
        __builtin_amdgcn_sched_barrier(0);
        __builtin_amdgcn_s_barrier();
    }

    const int col = jg0 + wn16 + fr;
    const int fq = lane >> 4;
    #pragma unroll
    for (int i = 0; i < 4; ++i) {
        #pragma unroll
        for (int reg = 0; reg < 4; ++reg) {
            const int t = t0 + wm + i * 16 + fq * 4 + reg;
            if (t < lim) {
                const int p = parent[t];
                const size_t xb = (size_t)t * FH + col;
                const float gi = acc[i][0][reg] + __half2float(xproj[xb]);
                const float go = acc[i][1][reg] + __half2float(xproj[xb + HD]);
                const float gf = acc[i][2][reg] + __half2float(xproj[xb + 2 * HD]);
                const float gu = acc[i][3][reg] + __half2float(xproj[xb + 3 * HD]);
                const float cp = c_buf[(size_t)(p + 1) * HD + col];
                const float c = fast_sig(gi) * fast_tanh(gu) + fast_sig(gf) * cp;
                const float h = fast_sig(go) * fast_tanh(c);
                c_buf[(size_t)(t + 1) * HD + col] = c;
                h_buf[(size_t)(t + 1) * HD + col] = f2bf(h);
                out[(size_t)t * HD + col] = h;
            }
        }
    }
}

extern "C" void kernel_launch(void* const* d_in, const int* in_sizes, int n_in,
                              void* d_out, int out_size, void* d_ws, size_t ws_size,
                              hipStream_t stream) {
    const float* feat   = (const float*)d_in[0];
    const float* Wx     = (const float*)d_in[1];
    const float* bx     = (const float*)d_in[2];
    const float* Wh     = (const float*)d_in[3];
    const float* bh     = (const float*)d_in[4];
    const int*   parent = (const int*)d_in[5];
    const float* root_c = (const float*)d_in[6];
    const float* root_h = (const float*)d_in[7];
    float* out = (float*)d_out;

    char* ws = (char*)d_ws;
    __half* xproj = (__half*)ws;                        ws += (size_t)NN * FH * 2;
    float* c_buf = (float*)ws;                          ws += (size_t)(NN + 1) * HD * 4;
    unsigned short* feat_b = (unsigned short*)ws;       ws += (size_t)NN * FEAT * 2;
    unsigned short* Wx_b = (unsigned short*)ws;         ws += (size_t)FH * FEAT * 2;
    unsigned short* Wh_b = (unsigned short*)ws;         ws += (size_t)FH * HD * 2;
    unsigned short* h_buf = (unsigned short*)ws;        ws += (size_t)(NN + 1) * HD * 2;
    int* done = (int*)ws;                               ws += 256;

    const size_t ntot = (size_t)NN * FEAT + (size_t)FH * FEAT + (size_t)FH * HD;
    convert_all_kernel<<<(unsigned)(ntot / 8 / 256), 256, 0, stream>>>(
        feat, Wx, Wh, feat_b, Wx_b, Wh_b, root_h, root_c, h_buf, c_buf, done);

    dim3 g1(NN / 256, FH / 256);
    xproj_8ph<<<g1, 512, 0, stream>>>(feat_b, Wx_b, bx, bh, xproj);

    // levels 0..9 (nodes 0..1022) fused: relaxed poll + pre-poll B staging
    levels_fused_small<<<224, 512, 0, stream>>>(
        xproj, Wh_b, h_buf, c_buf, out, done);

    // large levels: gather-free kk-split (R9-proven), 256 blocks each
    dim3 gl(16, 16);
    level_kk<64><<<gl, 512, 0, stream>>>(xproj, Wh_b, 1023, 511,
                                         h_buf, c_buf, out);
    level_kk<128><<<gl, 512, 0, stream>>>(xproj, Wh_b, 2047, 1023,
                                          h_buf, c_buf, out);
    level_kk<256><<<gl, 512, 0, stream>>>(xproj, Wh_b, 4095, 2047,
                                          h_buf, c_buf, out);

    // straggler node 8191 (parent 4095)
    dim3 g3(1, HD / 32);
    level_bk128_dbuf<<<g3, 256, 0, stream>>>(
        xproj, Wh_b, parent, h_buf, c_buf, out, 8191, 1);
}

// Round 18
// 435.762 us; speedup vs baseline: 1.2555x; 1.0475x over previous
//
#include <hip/hip_runtime.h>
#include <hip/hip_fp16.h>
#include <math.h>

#define FEAT 2048
#define HD 1024
#define FH 4096
#define NN 8192

using s16x8 = __attribute__((ext_vector_type(8))) short;
using f32x4 = __attribute__((ext_vector_type(4))) float;

#define GLOBAL_AS __attribute__((address_space(1)))
#define LDS_AS __attribute__((address_space(3)))

__device__ __forceinline__ void gload_lds16(const void* g, void* l) {
    __builtin_amdgcn_global_load_lds((const GLOBAL_AS unsigned int*)g,
                                     (LDS_AS unsigned int*)l, 16, 0, 0);
}

__device__ __forceinline__ unsigned short f2bf(float f) {
    union { float f; unsigned u; } v; v.f = f;
    unsigned r = v.u + 0x7FFFu + ((v.u >> 16) & 1u);  // RNE
    return (unsigned short)(r >> 16);
}

__device__ __forceinline__ float fast_sig(float x) { return 1.0f / (1.0f + __expf(-x)); }
__device__ __forceinline__ float fast_tanh(float x) {
    float ax = fabsf(x);
    float e = __expf(2.0f * ax);
    float r = 1.0f - 2.0f / (e + 1.0f);
    return copysignf(r, x);
}

// ---------------------------------------------------------------------------
// fused fp32 -> bf16 convert for feat, Wx, Wh  (+ root h/c init, fused)
// ---------------------------------------------------------------------------
__global__ __launch_bounds__(256) void convert_all_kernel(
    const float* __restrict__ feat, const float* __restrict__ Wx,
    const float* __restrict__ Wh, unsigned short* __restrict__ feat_b,
    unsigned short* __restrict__ Wx_b, unsigned short* __restrict__ Wh_b,
    const float* __restrict__ root_h, const float* __restrict__ root_c,
    unsigned short* __restrict__ h_buf, float* __restrict__ c_buf)
{
    const size_t g = (size_t)blockIdx.x * 256 + threadIdx.x;
    if (g < HD) { h_buf[g] = f2bf(root_h[g]); c_buf[g] = root_c[g]; }

    const size_t n1 = (size_t)NN * FEAT;
    const size_t n2 = n1 + (size_t)FH * FEAT;
    size_t i = g * 8;
    const float* s; unsigned short* d;
    if (i < n1)      { s = feat + i;        d = feat_b + i; }
    else if (i < n2) { s = Wx + (i - n1);   d = Wx_b + (i - n1); }
    else             { s = Wh + (i - n2);   d = Wh_b + (i - n2); }
    float4 a = *(const float4*)s;
    float4 b = *(const float4*)(s + 4);
    unsigned short r[8] = {f2bf(a.x), f2bf(a.y), f2bf(a.z), f2bf(a.w),
                           f2bf(b.x), f2bf(b.y), f2bf(b.z), f2bf(b.w)};
    *(s16x8*)d = *(const s16x8*)r;
}

// ---------------------------------------------------------------------------
// xproj = feat @ Wx^T + (bx+bh). 256x256 BK=64 kk-split (R7 schedule).
// fp16 output, written via LDS repack (R13: full-sector 16B/lane stores).
// ---------------------------------------------------------------------------
__global__ __launch_bounds__(512, 2) void xproj_8ph(
    const unsigned short* __restrict__ Ab,
    const unsigned short* __restrict__ Bb,
    const float* __restrict__ bx, const float* __restrict__ bh,
    __half* __restrict__ xproj)
{
    __shared__ char lds[131072];
    const int tid = threadIdx.x;
    const int wid = tid >> 6;
    const int lane = tid & 63;
    const int wr = wid >> 2;
    const int wc = wid & 3;
    const int bm = blockIdx.x * 256;
    const int bn = blockIdx.y * 256;
    const int fr = lane & 15;
    const int fq = lane >> 4;

    const int srow = tid >> 3;
    const int sslot = (tid & 7) ^ (srow & 7);
    const unsigned short* gA[4];
    const unsigned short* gB[4];
    #pragma unroll
    for (int q = 0; q < 4; ++q) {
        gA[q] = Ab + (size_t)(bm + q * 64 + srow) * FEAT + sslot * 8;
        gB[q] = Bb + (size_t)(bn + q * 64 + srow) * FEAT + sslot * 8;
    }
    const int ldsoff = tid * 16;

    f32x4 acc[8][4];
    #pragma unroll
    for (int i = 0; i < 8; ++i)
        #pragma unroll
        for (int j = 0; j < 4; ++j) { f32x4 z = {0.f, 0.f, 0.f, 0.f}; acc[i][j] = z; }

    #pragma unroll
    for (int q = 0; q < 4; ++q) {
        gload_lds16(gA[q], lds + q * 8192 + ldsoff);
        gload_lds16(gB[q], lds + 32768 + q * 8192 + ldsoff);
    }

    for (int t = 0; t < 32; ++t) {
        const int d = t & 1;
        const char* LA = lds + d * 65536;
        const char* LB = LA + 32768;
        char* SA = lds + (d ^ 1) * 65536;
        char* SB = SA + 32768;
        const int knext = (t + 1) * 64;

        asm volatile("s_waitcnt vmcnt(0)" ::: "memory");
        __builtin_amdgcn_s_barrier();

        #pragma unroll
        for (int kk = 0; kk < 2; ++kk) {
            const int kbyte = kk * 64 + fq * 16;
            s16x8 aF[8], bF[4];
            #pragma unroll
            for (int i = 0; i < 8; ++i) {
                const int row = wr * 128 + i * 16 + fr;
                aF[i] = *(const s16x8*)(LA + row * 128 + (kbyte ^ ((row & 7) << 4)));
            }
            #pragma unroll
            for (int j = 0; j < 4; ++j) {
                const int row = wc * 64 + j * 16 + fr;
                bF[j] = *(const s16x8*)(LB + row * 128 + (kbyte ^ ((row & 7) << 4)));
            }
            if (t < 31) {
                if (kk == 0) {
                    #pragma unroll
                    for (int q = 0; q < 4; ++q)
                        gload_lds16(gA[q] + knext, SA + q * 8192 + ldsoff);
                } else {
                    #pragma unroll
                    for (int q = 0; q < 4; ++q)
                        gload_lds16(gB[q] + knext, SB + q * 8192 + ldsoff);
                }
            }
            __builtin_amdgcn_s_setprio(1);
            #pragma unroll
            for (int i = 0; i < 8; ++i)
                #pragma unroll
                for (int j = 0; j < 4; ++j)
                    acc[i][j] = __builtin_amdgcn_mfma_f32_16x16x32_bf16(
                        aF[i], bF[j], acc[i][j], 0, 0, 0);
            __builtin_amdgcn_s_setprio(0);
        }
    }

    // ---- epilogue: LDS repack to coalesced fp16 stores ----
    __builtin_amdgcn_s_barrier();
    char* W = lds + wid * 16384;
    #pragma unroll
    for (int j = 0; j < 4; ++j) {
        const int c_loc = j * 16 + fr;
        const int col = bn + wc * 64 + c_loc;
        const float bias = bx[col] + bh[col];
        #pragma unroll
        for (int i = 0; i < 8; ++i) {
            #pragma unroll
            for (int reg = 0; reg < 4; ++reg) {
                const int r_loc = i * 16 + fq * 4 + reg;
                const int byteo = r_loc * 128 +
                    ((((c_loc >> 3) ^ (r_loc & 7)) << 4)) + (c_loc & 7) * 2;
                *(__half*)(W + byteo) = __float2half_rn(acc[i][j][reg] + bias);
            }
        }
    }
    asm volatile("s_waitcnt lgkmcnt(0)" ::: "memory");
    #pragma unroll
    for (int k = 0; k < 16; ++k) {
        const int f = k * 64 + lane;
        const int r_loc = f >> 3;
        const int cchunk = f & 7;
        const s16x8 v = *(const s16x8*)(W + r_loc * 128 +
                                        ((cchunk ^ (r_loc & 7)) << 4));
        const int grow = bm + wr * 128 + r_loc;
        const int gcol = bn + wc * 64 + cchunk * 8;
        *(s16x8*)((unsigned short*)xproj + (size_t)grow * FH + gcol) = v;
    }
}

// ---------------------------------------------------------------------------
// Large levels (R9-proven): gather-free, BK=64, 2-buffer. Parents contiguous:
// node t = start + r has parent prevstart + (r>>1). B: tile row r -> Wh row
// ((r>>4)&3)*1024 + jg0 + (r>>6)*16 + (r&15) -> gates in-register.
// ---------------------------------------------------------------------------
template<int BM>
__global__ __launch_bounds__(512, 2) void level_kk(
    const __half* __restrict__ xproj, const unsigned short* __restrict__ Whb,
    int start, int prevstart, unsigned short* __restrict__ h_buf,
    float* __restrict__ c_buf, float* __restrict__ out)
{
    constexpr int MR = BM / 32;
    constexpr int ABYTES = BM * 128;
    constexpr int BUF = ABYTES + 32768;
    __shared__ char lds[2 * BUF];
    const int tid = threadIdx.x;
    const int wid = tid >> 6, lane = tid & 63;
    const int wr = wid >> 2, wc = wid & 3;
    const int fr = lane & 15, fq = lane >> 4;
    const int t0 = start + blockIdx.x * BM;
    const int jg0 = blockIdx.y * 64;

    const int srow = tid >> 3;
    const int sslot = (tid & 7) ^ (srow & 7);
    const unsigned short* gA[BM / 64];
    #pragma unroll
    for (int q = 0; q < BM / 64; ++q) {
        const int rg = blockIdx.x * BM + q * 64 + srow;
        gA[q] = h_buf + (size_t)(prevstart + (rg >> 1) + 1) * HD + sslot * 8;
    }
    const unsigned short* gB[4];
    #pragma unroll
    for (int q = 0; q < 4; ++q) {
        const int r = q * 64 + srow;
        const int whrow = ((r >> 4) & 3) * 1024 + jg0 + ((r >> 6) * 16) + (r & 15);
        gB[q] = Whb + (size_t)whrow * HD + sslot * 8;
    }
    const int ldsoff = tid * 16;

    f32x4 acc[MR][4];
    #pragma unroll
    for (int i = 0; i < MR; ++i)
        #pragma unroll
        for (int j = 0; j < 4; ++j) { f32x4 z = {0.f, 0.f, 0.f, 0.f}; acc[i][j] = z; }

    #pragma unroll
    for (int q = 0; q < BM / 64; ++q)
        gload_lds16(gA[q], lds + q * 8192 + ldsoff);
    #pragma unroll
    for (int q = 0; q < 4; ++q)
        gload_lds16(gB[q], lds + ABYTES + q * 8192 + ldsoff);

    for (int t = 0; t < 16; ++t) {
        const char* LA = lds + (t & 1) * BUF;
        const char* LB = LA + ABYTES;
        char* SA = lds + ((t & 1) ^ 1) * BUF;
        char* SB = SA + ABYTES;
        const int knext = (t + 1) * 64;

        asm volatile("s_waitcnt vmcnt(0)" ::: "memory");
        __builtin_amdgcn_s_barrier();

        #pragma unroll
        for (int kk = 0; kk < 2; ++kk) {
            const int kbyte = kk * 64 + fq * 16;
            s16x8 aF[MR], bF[4];
            #pragma unroll
            for (int i = 0; i < MR; ++i) {
                const int row = wr * (BM / 2) + i * 16 + fr;
                aF[i] = *(const s16x8*)(LA + row * 128 + (kbyte ^ ((row & 7) << 4)));
            }
            #pragma unroll
            for (int j = 0; j < 4; ++j) {
                const int row = wc * 64 + j * 16 + fr;
                bF[j] = *(const s16x8*)(LB + row * 128 + (kbyte ^ ((row & 7) << 4)));
            }
            if (t < 15) {
                if (kk == 0) {
                    #pragma unroll
                    for (int q = 0; q < BM / 64; ++q)
                        gload_lds16(gA[q] + knext, SA + q * 8192 + ldsoff);
                } else {
                    #pragma unroll
                    for (int q = 0; q < 4; ++q)
                        gload_lds16(gB[q] + knext, SB + q * 8192 + ldsoff);
                }
            }
            __builtin_amdgcn_s_setprio(1);
            #pragma unroll
            for (int i = 0; i < MR; ++i)
                #pragma unroll
                for (int j = 0; j < 4; ++j)
                    acc[i][j] = __builtin_amdgcn_mfma_f32_16x16x32_bf16(
                        aF[i], bF[j], acc[i][j], 0, 0, 0);
            __builtin_amdgcn_s_setprio(0);
        }
    }

    const int col = jg0 + wc * 16 + fr;
    #pragma unroll
    for (int i = 0; i < MR; ++i) {
        #pragma unroll
        for (int reg = 0; reg < 4; ++reg) {
            const int t = t0 + wr * (BM / 2) + i * 16 + fq * 4 + reg;
            const int p = (t - 1) >> 1;
            const size_t xb = (size_t)t * FH + col;
            const float gi = acc[i][0][reg] + __half2float(xproj[xb]);
            const float go = acc[i][1][reg] + __half2float(xproj[xb + HD]);
            const float gf = acc[i][2][reg] + __half2float(xproj[xb + 2 * HD]);
            const float gu = acc[i][3][reg] + __half2float(xproj[xb + 3 * HD]);
            const float cp = c_buf[(size_t)(p + 1) * HD + col];
            const float c = fast_sig(gi) * fast_tanh(gu) + fast_sig(gf) * cp;
            const float h = fast_sig(go) * fast_tanh(c);
            c_buf[(size_t)(t + 1) * HD + col] = c;
            h_buf[(size_t)(t + 1) * HD + col] = f2bf(h);
            out[(size_t)t * HD + col] = h;
        }
    }
}

// ---------------------------------------------------------------------------
// Shared gate epilogue (small levels, parent[] gather path)
// ---------------------------------------------------------------------------
__device__ __forceinline__ void level_epilogue(
    f32x4 (&acc)[4][4], const __half* __restrict__ xproj,
    const int* __restrict__ parent, unsigned short* __restrict__ h_buf,
    float* __restrict__ c_buf, float* __restrict__ out,
    int t0, int lim, int wm, int col, int fq)
{
    #pragma unroll
    for (int i = 0; i < 4; ++i) {
        #pragma unroll
        for (int reg = 0; reg < 4; ++reg) {
            const int t = t0 + wm + i * 16 + fq * 4 + reg;
            if (t < lim) {
                const int p = parent[t];
                const size_t xb = (size_t)t * FH + col;
                const float gi = acc[i][0][reg] + __half2float(xproj[xb]);
                const float go = acc[i][1][reg] + __half2float(xproj[xb + HD]);
                const float gf = acc[i][2][reg] + __half2float(xproj[xb + 2 * HD]);
                const float gu = acc[i][3][reg] + __half2float(xproj[xb + 3 * HD]);
                const float cp = c_buf[(size_t)(p + 1) * HD + col];
                const float c = fast_sig(gi) * fast_tanh(gu) + fast_sig(gf) * cp;
                const float h = fast_sig(go) * fast_tanh(c);
                c_buf[(size_t)(t + 1) * HD + col] = c;
                h_buf[(size_t)(t + 1) * HD + col] = f2bf(h);
                out[(size_t)t * HD + col] = h;
            }
        }
    }
}

// ---------------------------------------------------------------------------
// BK=128 helpers (small levels)
// ---------------------------------------------------------------------------
__device__ __forceinline__ void bk128_issue(
    const unsigned short* const (&gA)[8], const unsigned short* const (&gB)[8],
    int k0, unsigned short* As, unsigned short* Bs, int wbase)
{
    #pragma unroll
    for (int q = 0; q < 8; ++q) {
        gload_lds16(gA[q] + k0, (char*)As + q * 4096 + wbase);
        gload_lds16(gB[q] + k0, (char*)Bs + q * 4096 + wbase);
    }
}

__device__ __forceinline__ void bk128_compute(
    const unsigned short* As, const unsigned short* Bs,
    f32x4 (&acc)[4][4], int wm, int wn16, int fr, int fkb)
{
    #pragma unroll
    for (int kk = 0; kk < 4; ++kk) {
        s16x8 aF[4], bF[4];
        #pragma unroll
        for (int i = 0; i < 4; ++i) {
            const int r = wm + i * 16 + fr;
            const int byteIn = (kk * 64 + fkb) ^ ((r & 7) << 4);
            aF[i] = *(const s16x8*)((const char*)As + r * 256 + byteIn);
        }
        #pragma unroll
        for (int g = 0; g < 4; ++g) {
            const int r = g * 32 + wn16 + fr;
            const int byteIn = (kk * 64 + fkb) ^ ((r & 7) << 4);
            bF[g] = *(const s16x8*)((const char*)Bs + r * 256 + byteIn);
        }
        #pragma unroll
        for (int i = 0; i < 4; ++i)
            #pragma unroll
            for (int g = 0; g < 4; ++g)
                acc[i][g] = __builtin_amdgcn_mfma_f32_16x16x32_bf16(aF[i], bF[g], acc[i][g], 0, 0, 0);
    }
}

// ---------------------------------------------------------------------------
// Small levels (count <= 512): BK=128 double-buffered (R5-proven)
// ---------------------------------------------------------------------------
__global__ __launch_bounds__(256) void level_bk128_dbuf(
    const __half* __restrict__ xproj, const unsigned short* __restrict__ Whb,
    const int* __restrict__ parent, unsigned short* __restrict__ h_buf,
    float* __restrict__ c_buf, float* __restrict__ out,
    int start, int count)
{
    __shared__ unsigned short As0[128 * 128];
    __shared__ unsigned short Bs0[128 * 128];
    __shared__ unsigned short As1[128 * 128];
    __shared__ unsigned short Bs1[128 * 128];
    const int tid = threadIdx.x;
    const int wid = tid >> 6;
    const int lane = tid & 63;
    const int t0 = start + blockIdx.x * 128;
    const int jg0 = blockIdx.y * 32;
    const int lim = start + count;
    const int wm = (wid & 1) * 64;
    const int wn16 = (wid >> 1) * 16;
    const int wbase = wid * 1024;
    const int srow_b = tid >> 4;
    const int rowbyte = (tid & 15) * 16;

    const unsigned short* gA[8];
    const unsigned short* gB[8];
    #pragma unroll
    for (int q = 0; q < 8; ++q) {
        const int r = q * 16 + srow_b;
        const int sk = (rowbyte ^ ((r & 7) << 4)) >> 1;
        const int tA = min(t0 + r, lim - 1);
        gA[q] = h_buf + (size_t)(parent[tA] + 1) * HD + sk;
        const int whrow = ((r >> 5) << 10) + jg0 + (r & 31);
        gB[q] = Whb + (size_t)whrow * HD + sk;
    }

    f32x4 acc[4][4];
    #pragma unroll
    for (int i = 0; i < 4; ++i)
        #pragma unroll
        for (int g = 0; g < 4; ++g) { f32x4 z = {0.f, 0.f, 0.f, 0.f}; acc[i][g] = z; }

    const int fr = lane & 15;
    const int fkb = (lane >> 4) * 16;

    bk128_issue(gA, gB, 0, As0, Bs0, wbase);
    #pragma unroll
    for (int t = 0; t < 8; ++t) {
        unsigned short* curA = (t & 1) ? As1 : As0;
        unsigned short* curB = (t & 1) ? Bs1 : Bs0;
        unsigned short* nxtA = (t & 1) ? As0 : As1;
        unsigned short* nxtB = (t & 1) ? Bs0 : Bs1;
        if (t < 7) {
            bk128_issue(gA, gB, (t + 1) * 128, nxtA, nxtB, wbase);
            asm volatile("s_waitcnt vmcnt(16)" ::: "memory");
        } else {
            asm volatile("s_waitcnt vmcnt(0)" ::: "memory");
        }
        __builtin_amdgcn_s_barrier();
        __builtin_amdgcn_sched_barrier(0);
        bk128_compute(curA, curB, acc, wm, wn16, fr, fkb);
        __builtin_amdgcn_sched_barrier(0);
        __builtin_amdgcn_s_barrier();
    }

    level_epilogue(acc, xproj, parent, h_buf, c_buf, out,
                   t0, lim, wm, jg0 + wn16 + fr, lane >> 4);
}

extern "C" void kernel_launch(void* const* d_in, const int* in_sizes, int n_in,
                              void* d_out, int out_size, void* d_ws, size_t ws_size,
                              hipStream_t stream) {
    const float* feat   = (const float*)d_in[0];
    const float* Wx     = (const float*)d_in[1];
    const float* bx     = (const float*)d_in[2];
    const float* Wh     = (const float*)d_in[3];
    const float* bh     = (const float*)d_in[4];
    const int*   parent = (const int*)d_in[5];
    const float* root_c = (const float*)d_in[6];
    const float* root_h = (const float*)d_in[7];
    float* out = (float*)d_out;

    char* ws = (char*)d_ws;
    __half* xproj = (__half*)ws;                        ws += (size_t)NN * FH * 2;
    float* c_buf = (float*)ws;                          ws += (size_t)(NN + 1) * HD * 4;
    unsigned short* feat_b = (unsigned short*)ws;       ws += (size_t)NN * FEAT * 2;
    unsigned short* Wx_b = (unsigned short*)ws;         ws += (size_t)FH * FEAT * 2;
    unsigned short* Wh_b = (unsigned short*)ws;         ws += (size_t)FH * HD * 2;
    unsigned short* h_buf = (unsigned short*)ws;        ws += (size_t)(NN + 1) * HD * 2;

    const size_t ntot = (size_t)NN * FEAT + (size_t)FH * FEAT + (size_t)FH * HD;
    convert_all_kernel<<<(unsigned)(ntot / 8 / 256), 256, 0, stream>>>(
        feat, Wx, Wh, feat_b, Wx_b, Wh_b, root_h, root_c, h_buf, c_buf);

    dim3 g1(NN / 256, FH / 256);
    xproj_8ph<<<g1, 512, 0, stream>>>(feat_b, Wx_b, bx, bh, xproj);

    // small levels (counts 1..512), gathered via parent[]
    for (int start = 0, sz = 1; sz <= 512; start += sz, sz *= 2) {
        dim3 g2((sz + 127) / 128, HD / 32);
        level_bk128_dbuf<<<g2, 256, 0, stream>>>(
            xproj, Wh_b, parent, h_buf, c_buf, out, start, sz);
    }

    // large levels: gather-free kk-split (R9-proven), 256 blocks each
    dim3 gl(16, 16);
    level_kk<64><<<gl, 512, 0, stream>>>(xproj, Wh_b, 1023, 511,
                                         h_buf, c_buf, out);
    level_kk<128><<<gl, 512, 0, stream>>>(xproj, Wh_b, 2047, 1023,
                                          h_buf, c_buf, out);
    level_kk<256><<<gl, 512, 0, stream>>>(xproj, Wh_b, 4095, 2047,
                                          h_buf, c_buf, out);

    // straggler node 8191 (parent 4095)
    dim3 g3(1, HD / 32);
    level_bk128_dbuf<<<g3, 256, 0, stream>>>(
        xproj, Wh_b, parent, h_buf, c_buf, out, 8191, 1);
}